// Round 27
// baseline (184.490 us; speedup 1.0000x reference)
//
#include <hip/hip_runtime.h>

#define BATCH 4096
#define SEQ   200
#define HID   128
#define ROWS  16
#define NTH   1024

typedef _Float16 f16;
typedef f16 f16x4 __attribute__((ext_vector_type(4)));
typedef f16 f16x8 __attribute__((ext_vector_type(8)));
typedef float f32x4 __attribute__((ext_vector_type(4)));

#define MFMA(a, b, c) __builtin_amdgcn_mfma_f32_16x16x32_f16((a), (b), (c), 0, 0, 0)

__device__ __forceinline__ float fast_exp2(float x) {
#if defined(__has_builtin) && __has_builtin(__builtin_amdgcn_exp2f)
    return __builtin_amdgcn_exp2f(x);
#else
    float r; asm volatile("v_exp_f32 %0, %1\n\ts_nop 0" : "=v"(r) : "v"(x)); return r;
#endif
}
__device__ __forceinline__ float fast_rcp(float x) {
#if defined(__has_builtin) && __has_builtin(__builtin_amdgcn_rcpf)
    return __builtin_amdgcn_rcpf(x);
#else
    float r; asm volatile("v_rcp_f32 %0, %1\n\ts_nop 0" : "=v"(r) : "v"(x)); return r;
#endif
}
#define LOG2E  1.442695041f
#define LOG2E2 2.885390082f

// Persistent GRU, v18: PRODUCER-CONSUMER WAVE SPECIALIZATION.
// Round 26 insight: VGPR_Count (120) excludes AGPRs — 96 weight frags live
// in AGPRs, true per-wave ~216 regs -> hard 2 waves/SIMD cap; >50% of each
// step is unhidden latency. Fix: split weights across roles. 1024-thr block
// = 16 waves: 8 X-waves hold ONLY kernel frags (48 regs) and compute next
// step's x-projections (one step ahead, v17 pipeline) + stage emb; 8
// H-waves hold ONLY rec_kernel frags (48 regs), read x-partials from LDS as
// MFMA C-init, run h-MFMAs + gates + h-scatter. Per-wave ~90-110 regs ->
// 4 waves/SIMD (2x latency hiding). if/else split keeps Bx and Br* live
// ranges disjoint (allocator reuses regs). Both branches execute IDENTICAL
// barrier counts (B1 common; B2,B3 prologue; 1/step) — required for
// wave-uniform divergent __syncthreads.
// xp exchange: [buf][gate][wave][lane][4] f32 -> per-wave contiguous 1024B
// b128 writes/reads, conflict-free. Transposed dataflow as v14-v17.
__global__ __attribute__((amdgpu_flat_work_group_size(NTH, NTH)))
void gru_mfma(const int* __restrict__ inputs,
              const float* __restrict__ emb,
              const float* __restrict__ kernel,
              const float* __restrict__ rec_kernel,
              const float* __restrict__ bias,
              float* __restrict__ out)
{
    __shared__ __align__(16) f16 xb[3][4][64][8];        // x^T frags, triple buf, 12 KB
    __shared__ __align__(16) f16 hb[2][4][64][8];        // h^T frags, dbuf, 8 KB
    __shared__ __align__(16) float xp[2][3][8][64][4];   // x-proj partials, 48 KB
    __shared__ int tok_sh[2][ROWS];
    __shared__ int ts_sh;

    const int tid  = threadIdx.x;
    const int lane = tid & 63;
    const int wv   = tid >> 6;          // 0..15
    const bool isX = (wv < 8);
    const int w    = isX ? wv : (wv - 8);   // col-slice 0..7
    const int j0   = w * 16;
    const int l15  = lane & 15;         // batch index within tile
    const int hi   = lane >> 4;
    const int r0   = hi * 4;            // out_col = j0+r0+i
    const int row0 = blockIdx.x * ROWS;

    // int32-vs-int64 token stride, detected from data (int64 LE: odd words 0)
    if (tid == 0) { int any = 0; for (int i = 1; i < 128; i += 2) any |= inputs[i]; ts_sh = any ? 1 : 2; }

    // zero hb[0] (step-0 scatter fully covers hb[1])
    for (int i = tid; i < 4 * 64 * 8; i += NTH) ((f16*)hb)[i] = (f16)0.f;
    __syncthreads();                    // B1
    const int ts = ts_sh;

    if (isX) {
        // ================= X half: x-projection producer =================
        f16x8 Bx[3][4];                 // kernel frags: z,r x -LOG2E; h x +LOG2E2
        const float gsc[3] = { -LOG2E, -LOG2E, LOG2E2 };
#pragma unroll
        for (int g = 0; g < 3; ++g)
#pragma unroll
            for (int kt = 0; kt < 4; ++kt) {
                f16x8 t;
#pragma unroll
                for (int e = 0; e < 8; ++e)
                    t[e] = (f16)(gsc[g] * kernel[(size_t)(kt * 32 + hi * 8 + e) * 384 + g * HID + j0 + l15]);
                Bx[g][kt] = t;
            }
        f32x4 bzv, brv, bxhv;
#pragma unroll
        for (int i = 0; i < 4; ++i) {
            const int c = j0 + r0 + i;
            bzv[i]  = -LOG2E * (bias[c]       + bias[384 + c]);
            brv[i]  = -LOG2E * (bias[128 + c] + bias[512 + c]);
            bxhv[i] =  LOG2E2 * bias[256 + c];
        }

        // stager: 512 X-threads, each owns half a 16B fragment unit
        const int skt   = (tid >> 7) & 3;
        const int sidx  = tid & 127;
        const int su    = sidx >> 1;
        const int shalf = sidx & 1;
        const int sb    = su & 15;
        const int shid  = skt * 32 + (su >> 4) * 8 + shalf * 4;
        const int sw    = (skt * 64 + su) * 8 + shalf * 4;
        const bool twr  = (tid < 32) && ((tid & 1) == 0);

        const size_t tbase = (size_t)(row0 + sb) * SEQ;
        const int tok0 = inputs[(tbase + 0) * ts];
        int t1 = inputs[(tbase + 1) * ts];
        int t2 = inputs[(tbase + 2) * ts];
        if (twr) tok_sh[0][sb] = tok0;
        {
            const float4 v0 = *(const float4*)&emb[(size_t)tok0 * HID + shid];
            const float4 v1 = *(const float4*)&emb[(size_t)t1   * HID + shid];
            f16x4 a; a[0] = (f16)v0.x; a[1] = (f16)v0.y; a[2] = (f16)v0.z; a[3] = (f16)v0.w;
            f16x4 b; b[0] = (f16)v1.x; b[1] = (f16)v1.y; b[2] = (f16)v1.z; b[3] = (f16)v1.w;
            *(f16x4*)&((f16*)xb)[sw] = a;
            *(f16x4*)&((f16*)xb)[1 * (4 * 64 * 8) + sw] = b;
        }
        __syncthreads();                // B2: xb0/xb1/tok0 visible

        // xp[0] from xb[0]
        {
            f32x4 azx = bzv, arx = brv, axc = bxhv;
#pragma unroll
            for (int kt = 0; kt < 4; ++kt) {
                const f16x8 xB = *(const f16x8*)&xb[0][kt][lane][0];
                azx = MFMA(Bx[0][kt], xB, azx);
                arx = MFMA(Bx[1][kt], xB, arx);
                axc = MFMA(Bx[2][kt], xB, axc);
            }
            *(f32x4*)&xp[0][0][w][lane][0] = azx;
            *(f32x4*)&xp[0][1][w][lane][0] = arx;
            *(f32x4*)&xp[0][2][w][lane][0] = axc;
        }
        __syncthreads();                // B3

        int rd_x = 1, wr_x = 2;
        for (int s = 0; s < SEQ; ++s) {
            const int nxt = (s & 1) ^ 1;
            const bool pf1 = (s + 1 < SEQ);
            const bool pf2 = (s + 2 < SEQ);
            float4 pv; int t3 = t2;
            if (pf2) {   // load x(s+2) at top; consumed after xp compute
                pv = *(const float4*)&emb[(size_t)t2 * HID + shid];
                const int s3 = (s + 3 < SEQ) ? (s + 3) : (SEQ - 1);
                t3 = inputs[(tbase + s3) * ts];
            }
            if (pf1) {   // xp for step s+1 from xb[rd_x] = x(s+1)
                f32x4 azx = bzv, arx = brv, axc = bxhv;
#pragma unroll
                for (int kt = 0; kt < 4; ++kt) {
                    const f16x8 xB = *(const f16x8*)&xb[rd_x][kt][lane][0];
                    azx = MFMA(Bx[0][kt], xB, azx);
                    arx = MFMA(Bx[1][kt], xB, arx);
                    axc = MFMA(Bx[2][kt], xB, axc);
                }
                *(f32x4*)&xp[nxt][0][w][lane][0] = azx;
                *(f32x4*)&xp[nxt][1][w][lane][0] = arx;
                *(f32x4*)&xp[nxt][2][w][lane][0] = axc;
                if (twr) tok_sh[nxt][sb] = t1;
            }
            if (pf2) {   // convert + stage x(s+2)
                f16x4 xv; xv[0] = (f16)pv.x; xv[1] = (f16)pv.y; xv[2] = (f16)pv.z; xv[3] = (f16)pv.w;
                *(f16x4*)&((f16*)xb)[wr_x * (4 * 64 * 8) + sw] = xv;
            }
            t1 = t2; t2 = t3;
            rd_x = (rd_x == 2) ? 0 : rd_x + 1;
            wr_x = (wr_x == 2) ? 0 : wr_x + 1;
            __syncthreads();            // loop barrier
        }
    } else {
        // ================= H half: recurrence consumer =================
        f16x8 Brz[4], Brr[4], Brh[4];   // rec_kernel frags only
#pragma unroll
        for (int kt = 0; kt < 4; ++kt) {
            f16x8 tz, tr, th;
#pragma unroll
            for (int e = 0; e < 8; ++e) {
                const size_t krow = (size_t)(kt * 32 + hi * 8 + e) * 384;
                tz[e] = (f16)(-LOG2E  * rec_kernel[krow + j0 + l15]);
                tr[e] = (f16)(-LOG2E  * rec_kernel[krow + HID + j0 + l15]);
                th[e] = (f16)(LOG2E2 * rec_kernel[krow + 2 * HID + j0 + l15]);
            }
            Brz[kt] = tz; Brr[kt] = tr; Brh[kt] = th;
        }
        f32x4 brhv;
#pragma unroll
        for (int i = 0; i < 4; ++i) brhv[i] = LOG2E2 * bias[640 + j0 + r0 + i];

        f32x4 h = {0.f, 0.f, 0.f, 0.f};
        const int hk  = j0 + r0;
        const int hwi = (((hk >> 5) * 64) + (((hk & 31) >> 3) * 16) + l15) * 8 + (hk & 7);

        __syncthreads();                // B2 (match X)
        __syncthreads();                // B3 (match X)

        for (int s = 0; s < SEQ; ++s) {
            const int cur = s & 1, nxt = cur ^ 1;
            // C-init from producer partials (includes x-proj + z/r/xh biases)
            f32x4 az  = *(const f32x4*)&xp[cur][0][w][lane][0];
            f32x4 ar  = *(const f32x4*)&xp[cur][1][w][lane][0];
            const f32x4 axc = *(const f32x4*)&xp[cur][2][w][lane][0];
            f32x4 ah  = brhv;
            const int tkk = tok_sh[cur][l15];
#pragma unroll
            for (int kt = 0; kt < 4; ++kt) {
                const f16x8 hB = *(const f16x8*)&hb[cur][kt][lane][0];
                az = MFMA(Brz[kt], hB, az);
                ar = MFMA(Brr[kt], hB, ar);
                ah = MFMA(Brh[kt], hB, ah);
            }
            f16x4 hv;
#pragma unroll
            for (int i = 0; i < 4; ++i) {
                const float z  = fast_rcp(1.f + fast_exp2(az[i]));
                const float rg = fast_rcp(1.f + fast_exp2(ar[i]));
                const float u  = axc[i] + rg * ah[i];         // 2*log2e-scaled
                const float hh = 1.f - 2.f * fast_rcp(1.f + fast_exp2(u));
                const float hn = hh + z * (h[i] - hh);
                h[i] = (tkk != 0) ? hn : h[i];
                hv[i] = (f16)h[i];
            }
            *(f16x4*)&((f16*)hb)[nxt * (4 * 64 * 8) + hwi] = hv;
            __syncthreads();            // loop barrier
        }

        float4 o; o.x = h[0]; o.y = h[1]; o.z = h[2]; o.w = h[3];
        *(float4*)&out[(size_t)(row0 + l15) * HID + j0 + r0] = o;
    }
}

extern "C" void kernel_launch(void* const* d_in, const int* in_sizes, int n_in,
                              void* d_out, int out_size, void* d_ws, size_t ws_size,
                              hipStream_t stream) {
    const int* inputs      = (const int*)d_in[0];
    const float* emb       = (const float*)d_in[1];
    const float* kernel    = (const float*)d_in[2];
    const float* rec_k     = (const float*)d_in[3];
    const float* bias      = (const float*)d_in[4];
    float* out             = (float*)d_out;
    gru_mfma<<<BATCH / ROWS, NTH, 0, stream>>>(inputs, emb, kernel, rec_k, bias, out);
}